// Round 5
// baseline (422.649 us; speedup 1.0000x reference)
//
#include <hip/hip_runtime.h>

// Segment-sum via counting-sort CSR + gather-reduce.
// R5: deterministic rank scatter (no atomic-returns in scatter), single-block
// scan (1 dispatch), reduce unrolled x4 (16 edge_w loads in flight per wave).

__global__ __launch_bounds__(256) void hist_rank_kernel(
    const int* __restrict__ edge0, int* __restrict__ counts,
    int* __restrict__ rank, int E)
{
    int t = blockIdx.x * blockDim.x + threadIdx.x;
    int base = t * 4;
    if (base + 3 < E) {
        int4 r = ((const int4*)edge0)[t];
        int4 k;
        k.x = atomicAdd(&counts[r.x], 1);
        k.y = atomicAdd(&counts[r.y], 1);
        k.z = atomicAdd(&counts[r.z], 1);
        k.w = atomicAdd(&counts[r.w], 1);
        ((int4*)rank)[t] = k;
    } else {
        for (int i = base; i < E; ++i) rank[i] = atomicAdd(&counts[edge0[i]], 1);
    }
}

// Single-block exclusive scan of counts[0..N) -> offsets; offsets[N] = E.
__global__ __launch_bounds__(1024) void scan_kernel(
    const int* __restrict__ counts, int* __restrict__ offsets, int N, int E)
{
    __shared__ int wtot[16];
    int t = threadIdx.x;
    int per = (N + 1023) / 1024;
    int b0 = t * per;
    int b1 = min(N, b0 + per);
    int s = 0;
    for (int i = b0; i < b1; ++i) s += counts[i];
    int lane = t & 63, wv = t >> 6;
    int inc = s;
    for (int off = 1; off < 64; off <<= 1) {
        int u = __shfl_up(inc, off);
        if (lane >= off) inc += u;
    }
    if (lane == 63) wtot[wv] = inc;
    __syncthreads();
    int wpre = 0;
    for (int w = 0; w < wv; ++w) wpre += wtot[w];
    int pre = wpre + (inc - s);            // exclusive prefix of this thread's range
    for (int i = b0; i < b1; ++i) { offsets[i] = pre; pre += counts[i]; }
    if (t == 0) offsets[N] = E;
}

// Deterministic scatter: no atomics, no dependence chains.
__global__ __launch_bounds__(256) void scatter_kernel(
    const int* __restrict__ edge0, const int* __restrict__ rank,
    const int* __restrict__ offsets, int* __restrict__ ids, int E)
{
    int t = blockIdx.x * blockDim.x + threadIdx.x;
    int base = t * 4;
    if (base + 3 < E) {
        int4 r = ((const int4*)edge0)[t];
        int4 k = ((const int4*)rank)[t];
        ids[offsets[r.x] + k.x] = base;
        ids[offsets[r.y] + k.y] = base + 1;
        ids[offsets[r.z] + k.z] = base + 2;
        ids[offsets[r.w] + k.w] = base + 3;
    } else {
        for (int i = base; i < E; ++i) ids[offsets[edge0[i]] + rank[i]] = i;
    }
}

// 1 wave per row. lane = 16*sub + q: sub = one of 4 concurrent edges,
// q = float4 feature-group. Main loop: 4 edges/lane -> 16 loads in flight.
__global__ __launch_bounds__(256) void reduce_kernel(
    const int* __restrict__ offsets, const int* __restrict__ ids,
    const float4* __restrict__ w4, float4* __restrict__ out4, int N)
{
    int row = blockIdx.x * 4 + (threadIdx.x >> 6);
    if (row >= N) return;
    int lane = threadIdx.x & 63;
    int sub = lane >> 4, q = lane & 15;
    int beg = offsets[row], end = offsets[row + 1];
    float4 acc = make_float4(0.f, 0.f, 0.f, 0.f);
    int j = beg + sub;
    for (; j + 12 < end; j += 16) {                 // 16 edges per wave-iter
        int e0 = ids[j], e1 = ids[j + 4], e2 = ids[j + 8], e3 = ids[j + 12];
        float4 w0 = w4[(size_t)e0 * 16 + q];
        float4 w1 = w4[(size_t)e1 * 16 + q];
        float4 w2 = w4[(size_t)e2 * 16 + q];
        float4 w3 = w4[(size_t)e3 * 16 + q];
        acc.x += (w0.x + w1.x) + (w2.x + w3.x);
        acc.y += (w0.y + w1.y) + (w2.y + w3.y);
        acc.z += (w0.z + w1.z) + (w2.z + w3.z);
        acc.w += (w0.w + w1.w) + (w2.w + w3.w);
    }
    for (; j + 4 < end; j += 8) {                   // 8 edges per wave-iter
        int e0 = ids[j], e1 = ids[j + 4];
        float4 w0 = w4[(size_t)e0 * 16 + q];
        float4 w1 = w4[(size_t)e1 * 16 + q];
        acc.x += w0.x + w1.x; acc.y += w0.y + w1.y;
        acc.z += w0.z + w1.z; acc.w += w0.w + w1.w;
    }
    if (j < end) {
        int e = ids[j];
        float4 w = w4[(size_t)e * 16 + q];
        acc.x += w.x; acc.y += w.y; acc.z += w.z; acc.w += w.w;
    }
    acc.x += __shfl_xor(acc.x, 16); acc.y += __shfl_xor(acc.y, 16);
    acc.z += __shfl_xor(acc.z, 16); acc.w += __shfl_xor(acc.w, 16);
    acc.x += __shfl_xor(acc.x, 32); acc.y += __shfl_xor(acc.y, 32);
    acc.z += __shfl_xor(acc.z, 32); acc.w += __shfl_xor(acc.w, 32);
    if (sub == 0) out4[(size_t)row * 16 + q] = acc;
}

extern "C" void kernel_launch(void* const* d_in, const int* in_sizes, int n_in,
                              void* d_out, int out_size, void* d_ws, size_t ws_size,
                              hipStream_t stream) {
    const int*   edge   = (const int*)d_in[0];     // (2,E) int32; rows = edge[0,:]
    const float* edge_w = (const float*)d_in[1];   // (E, 64) float32
    int E = in_sizes[0] / 2;
    int N = out_size / 64;

    // Workspace (int32): [counts N][offsets N+1][rank E][ids E]
    int* counts  = (int*)d_ws;
    int* offsets = counts + N;
    int* rank    = offsets + N + 1;
    int* ids     = rank + E;

    (void)hipMemsetAsync(counts, 0, (size_t)N * sizeof(int), stream);

    int blocksE = (E + 1023) / 1024;               // 4 edges per thread
    hist_rank_kernel<<<blocksE, 256, 0, stream>>>(edge, counts, rank, E);
    scan_kernel<<<1, 1024, 0, stream>>>(counts, offsets, N, E);
    scatter_kernel<<<blocksE, 256, 0, stream>>>(edge, rank, offsets, ids, E);

    int blocksR = (N + 3) / 4;
    reduce_kernel<<<blocksR, 256, 0, stream>>>(offsets, ids, (const float4*)edge_w,
                                               (float4*)d_out, N);
}